// Round 1
// baseline (919.338 us; speedup 1.0000x reference)
//
#include <hip/hip_runtime.h>
#include <math.h>

typedef __attribute__((ext_vector_type(8))) short s16x8;
typedef __attribute__((ext_vector_type(4))) short s16x4;
typedef __attribute__((ext_vector_type(4))) float f32x4;

#define DEVINL __device__ __forceinline__

DEVINL short f2bf(float f) {
    unsigned u = __float_as_uint(f);
    u += 0x7fffu + ((u >> 16) & 1u);   // RNE (finite values)
    return (short)(u >> 16);
}
DEVINL float softplusf(float x) { return (x > 20.f) ? x : log1pf(expf(x)); }
DEVINL float siluf(float z) { return z / (1.f + expf(-z)); }

// ---------------------------------------------------------------------------
// LN over C=128 for each (b,l), reading x[b,c,l] (transposed) -> bf16 [8192,128]
__global__ __launch_bounds__(256) void ln1_kernel(const float* __restrict__ x,
    const float* __restrict__ g, const float* __restrict__ bb, short* __restrict__ out)
{
    __shared__ float tile[64 * 129];
    int b = blockIdx.x >> 6;
    int l0 = (blockIdx.x & 63) << 6;
    int t = threadIdx.x;
    int ll = t & 63, c0 = t >> 6;
    for (int c = c0; c < 128; c += 4)
        tile[ll * 129 + c] = x[((size_t)(b * 128 + c) << 12) + l0 + ll];
    __syncthreads();
    int r = t >> 2, q = t & 3;
    float s1 = 0.f, s2 = 0.f;
    #pragma unroll 8
    for (int j = 0; j < 32; ++j) {
        float v = tile[r * 129 + q * 32 + j];
        s1 += v; s2 += v * v;
    }
    s1 += __shfl_xor(s1, 1); s2 += __shfl_xor(s2, 1);
    s1 += __shfl_xor(s1, 2); s2 += __shfl_xor(s2, 2);
    float mean = s1 * (1.f / 128.f);
    float var  = s2 * (1.f / 128.f) - mean * mean;
    float rstd = rsqrtf(var + 1e-5f);
    short* orow = out + ((size_t)((b << 12) + l0 + r) << 7);
    for (int j = 0; j < 32; j += 4) {
        int c = q * 32 + j;
        s16x4 pk;
        #pragma unroll
        for (int i = 0; i < 4; ++i)
            pk[i] = f2bf((tile[r * 129 + c + i] - mean) * rstd * g[c + i] + bb[c + i]);
        *(s16x4*)&orow[c] = pk;
    }
}

// LN over L=4096 for each row m=(b,t) -> bf16 [256,4096]
__global__ __launch_bounds__(256) void ln2_kernel(const float* __restrict__ x,
    const float* __restrict__ g, const float* __restrict__ bb, short* __restrict__ out)
{
    int m = blockIdx.x, t = threadIdx.x;
    const float* row = x + (size_t)m * 4096;
    f32x4 vals[4];
    float s1 = 0.f, s2 = 0.f;
    #pragma unroll
    for (int j = 0; j < 4; ++j) {
        vals[j] = *(const f32x4*)(row + j * 1024 + t * 4);
        #pragma unroll
        for (int i = 0; i < 4; ++i) { s1 += vals[j][i]; s2 += vals[j][i] * vals[j][i]; }
    }
    #pragma unroll
    for (int off = 32; off; off >>= 1) { s1 += __shfl_xor(s1, off); s2 += __shfl_xor(s2, off); }
    __shared__ float red[8];
    int wv = t >> 6;
    if ((t & 63) == 0) { red[wv] = s1; red[4 + wv] = s2; }
    __syncthreads();
    s1 = red[0] + red[1] + red[2] + red[3];
    s2 = red[4] + red[5] + red[6] + red[7];
    float mean = s1 * (1.f / 4096.f);
    float var  = s2 * (1.f / 4096.f) - mean * mean;
    float rstd = rsqrtf(var + 1e-5f);
    short* orow = out + (size_t)m * 4096;
    #pragma unroll
    for (int j = 0; j < 4; ++j) {
        int idx = j * 1024 + t * 4;
        f32x4 gv = *(const f32x4*)(g + idx);
        f32x4 bv = *(const f32x4*)(bb + idx);
        s16x4 pk;
        #pragma unroll
        for (int i = 0; i < 4; ++i)
            pk[i] = f2bf((vals[j][i] - mean) * rstd * gv[i] + bv[i]);
        *(s16x4*)&orow[idx] = pk;
    }
}

// ---------------------------------------------------------------------------
// GEMM: C[m,n] = sum_k A[m,k] * W[n,k].  A bf16 [M,K] row-major, W fp32 [N,K]
// row-major (converted to bf16 in-flight). 256 threads = 4 waves stacked in M.
// grid = (N/BN, M/BM, nsplit); k chunk = kLen per z.
template<int BM, int BN, int EPI>
__global__ __launch_bounds__(256) void gemm_bt(
    const short* __restrict__ A, const float* __restrict__ W,
    float* __restrict__ C, const float* __restrict__ bias,
    int M, int Nreal, int K, int kLen, int ldc)
{
    constexpr int LK = 72;  // padded K stride (bf16 elems) -> conflict-free-ish
    __shared__ short Al[BM * LK];
    __shared__ short Wl[BN * LK];
    const int tid = threadIdx.x;
    const int lane = tid & 63;
    const int wv = tid >> 6;
    const int lr = lane & 15, kh = lane >> 4;
    const int n0 = blockIdx.x * BN;
    const int m0 = blockIdx.y * BM;
    const int k0 = blockIdx.z * kLen;
    constexpr int FM = BM / 64, FN = BN / 16;
    f32x4 acc[FM][FN];
    #pragma unroll
    for (int a = 0; a < FM; ++a)
        #pragma unroll
        for (int b = 0; b < FN; ++b) acc[a][b] = (f32x4){0.f, 0.f, 0.f, 0.f};

    for (int kt = 0; kt < kLen; kt += 64) {
        const int kg = k0 + kt;
        {   // stage A tile: BM x 64 bf16
            int ar = tid >> 3, ac = tid & 7;
            #pragma unroll
            for (int i = 0; i < BM / 32; ++i) {
                int row = ar + i * 32;
                s16x8 v = *(const s16x8*)(A + (size_t)(m0 + row) * K + kg + ac * 8);
                *(s16x8*)&Al[row * LK + ac * 8] = v;
            }
        }
        {   // stage W tile: BN x 64 fp32 -> bf16
            #pragma unroll
            for (int j = 0; j < (BN * 16) / 256; ++j) {
                int chunk = tid + j * 256;
                int row = chunk >> 4, cc = chunk & 15;
                int gn = n0 + row;
                f32x4 v;
                if (gn < Nreal) v = *(const f32x4*)(W + (size_t)gn * K + kg + cc * 4);
                else            v = (f32x4){0.f, 0.f, 0.f, 0.f};
                s16x4 pk;
                #pragma unroll
                for (int i = 0; i < 4; ++i) pk[i] = f2bf(v[i]);
                *(s16x4*)&Wl[row * LK + cc * 4] = pk;
            }
        }
        __syncthreads();
        #pragma unroll
        for (int ks = 0; ks < 64; ks += 32) {
            s16x8 af[FM], bfr[FN];
            #pragma unroll
            for (int mi = 0; mi < FM; ++mi)
                af[mi] = *(const s16x8*)&Al[(wv * (BM / 4) + mi * 16 + lr) * LK + ks + kh * 8];
            #pragma unroll
            for (int ni = 0; ni < FN; ++ni)
                bfr[ni] = *(const s16x8*)&Wl[(ni * 16 + lr) * LK + ks + kh * 8];
            #pragma unroll
            for (int mi = 0; mi < FM; ++mi)
                #pragma unroll
                for (int ni = 0; ni < FN; ++ni)
                    acc[mi][ni] = __builtin_amdgcn_mfma_f32_16x16x32_bf16(
                        af[mi], bfr[ni], acc[mi][ni], 0, 0, 0);
        }
        __syncthreads();
    }
    float* Cz = C + (size_t)blockIdx.z * M * ldc;
    #pragma unroll
    for (int mi = 0; mi < FM; ++mi) {
        #pragma unroll
        for (int ni = 0; ni < FN; ++ni) {
            int gn = n0 + ni * 16 + lr;
            #pragma unroll
            for (int j = 0; j < 4; ++j) {
                int gm = m0 + wv * (BM / 4) + mi * 16 + kh * 4 + j;
                float v = acc[mi][ni][j];
                if constexpr (EPI == 1) v = softplusf(v + bias[gn]);
                Cz[(size_t)gm * ldc + gn] = v;
            }
        }
    }
}

// ---------------------------------------------------------------------------
// depthwise causal conv (K=4) + silu; m1: seq=4096,d=256
__global__ __launch_bounds__(256) void conv1_kernel(const float* __restrict__ xz,
    const float* __restrict__ cw, const float* __restrict__ cb,
    float* __restrict__ xcf, short* __restrict__ xcb)
{
    int idx = blockIdx.x * 256 + threadIdx.x;      // 2*4096*256
    int d = idx & 255;
    int l = (idx >> 8) & 4095;
    int b = idx >> 20;
    f32x4 wv = *(const f32x4*)(cw + d * 4);
    float acc = cb[d];
    #pragma unroll
    for (int j = 0; j < 4; ++j) {
        int ll = l - 3 + j;
        if (ll >= 0) acc += xz[((size_t)((b << 12) + ll) << 9) + d] * wv[j];
    }
    acc = siluf(acc);
    size_t o = ((size_t)((b << 12) + l) << 8) + d;
    xcf[o] = acc;
    xcb[o] = f2bf(acc);
}

// m2: seq=128, d=8192
__global__ __launch_bounds__(256) void conv2_kernel(const float* __restrict__ xz,
    const float* __restrict__ cw, const float* __restrict__ cb,
    float* __restrict__ xcf, short* __restrict__ xcb)
{
    int idx = blockIdx.x * 256 + threadIdx.x;      // 2*128*8192
    int d = idx & 8191;
    int t = (idx >> 13) & 127;
    int b = idx >> 20;
    f32x4 wv = *(const f32x4*)(cw + d * 4);
    float acc = cb[d];
    #pragma unroll
    for (int j = 0; j < 4; ++j) {
        int tt = t - 3 + j;
        if (tt >= 0) acc += xz[((size_t)((b << 7) + tt) << 14) + d] * wv[j];
    }
    acc = siluf(acc);
    size_t o = ((size_t)((b << 7) + t) << 13) + d;
    xcf[o] = acc;
    xcb[o] = f2bf(acc);
}

// ---------------------------------------------------------------------------
// m1 delta: softplus(dt[m,0:8] @ dt_w[d,0:8]^T + dt_b[d]) -> [8192,256]
__global__ __launch_bounds__(256) void dtproj1_kernel(const float* __restrict__ dbl,
    const float* __restrict__ dtw, const float* __restrict__ dtb, float* __restrict__ delta)
{
    int m = blockIdx.x;
    int d = threadIdx.x;
    const float* dtv = dbl + (size_t)m * 32;
    f32x4 w0 = *(const f32x4*)(dtw + d * 8);
    f32x4 w1 = *(const f32x4*)(dtw + d * 8 + 4);
    float acc = dtb[d];
    #pragma unroll
    for (int j = 0; j < 4; ++j) acc += dtv[j] * w0[j];
    #pragma unroll
    for (int j = 0; j < 4; ++j) acc += dtv[4 + j] * w1[j];
    delta[(size_t)m * 256 + d] = softplusf(acc);
}

// ---------------------------------------------------------------------------
// m1 chunked scan.  64 chunks x 64 steps.  dbl row stride 32: B at +8, C at +16.
__global__ __launch_bounds__(256) void scan1_p1(const float* __restrict__ delta,
    const float* __restrict__ xc, const float* __restrict__ dbl,
    const float* __restrict__ alog, float* __restrict__ hch, float* __restrict__ pch)
{
    int b = blockIdx.x >> 6, ch = blockIdx.x & 63;
    int d = threadIdx.x;
    __shared__ float bc[1024];
    for (int i = threadIdx.x; i < 1024; i += 256) {
        int j = i >> 4, s = i & 15;
        bc[i] = dbl[(size_t)((b << 12) + (ch << 6) + j) * 32 + 8 + s];
    }
    float a[8], h[8], P[8];
    #pragma unroll
    for (int s = 0; s < 8; ++s) { a[s] = -expf(alog[d * 8 + s]); h[s] = 0.f; P[s] = 1.f; }
    __syncthreads();
    for (int j = 0; j < 64; ++j) {
        size_t row = (b << 12) + (ch << 6) + j;
        float dl = delta[(row << 8) + d];
        float xv = xc[(row << 8) + d];
        float dx = dl * xv;
        #pragma unroll
        for (int s = 0; s < 8; ++s) {
            float dA = expf(dl * a[s]);
            h[s] = dA * h[s] + dx * bc[(j << 4) + s];
            P[s] *= dA;
        }
    }
    size_t base = (((size_t)((b << 6) + ch) << 8) + d) << 3;
    #pragma unroll
    for (int s = 0; s < 8; ++s) { hch[base + s] = h[s]; pch[base + s] = P[s]; }
}

__global__ __launch_bounds__(256) void scan1_p2(const float* __restrict__ hch,
    const float* __restrict__ pch, float* __restrict__ hin)
{
    int b = blockIdx.x >> 3;
    int idx = ((blockIdx.x & 7) << 8) + threadIdx.x;   // 0..2047 = d*8+s
    float h = 0.f;
    for (int c = 0; c < 64; ++c) {
        size_t o = (((size_t)((b << 6) + c)) << 11) + idx;
        hin[o] = h;
        h = pch[o] * h + hch[o];
    }
}

__global__ __launch_bounds__(256) void scan1_p3(const float* __restrict__ delta,
    const float* __restrict__ xc, const float* __restrict__ dbl,
    const float* __restrict__ alog, const float* __restrict__ hin,
    const float* __restrict__ Dw, const float* __restrict__ xz,
    short* __restrict__ ybf)
{
    int b = blockIdx.x >> 6, ch = blockIdx.x & 63;
    int d = threadIdx.x;
    __shared__ float bc[1024];
    for (int i = threadIdx.x; i < 1024; i += 256) {
        int j = i >> 4, s = i & 15;
        bc[i] = dbl[(size_t)((b << 12) + (ch << 6) + j) * 32 + 8 + s];
    }
    float a[8], h[8];
    size_t base = (((size_t)((b << 6) + ch) << 8) + d) << 3;
    #pragma unroll
    for (int s = 0; s < 8; ++s) { a[s] = -expf(alog[d * 8 + s]); h[s] = hin[base + s]; }
    float Dv = Dw[d];
    __syncthreads();
    for (int j = 0; j < 64; ++j) {
        size_t row = (b << 12) + (ch << 6) + j;
        float dl = delta[(row << 8) + d];
        float xv = xc[(row << 8) + d];
        float dx = dl * xv;
        float y = 0.f;
        #pragma unroll
        for (int s = 0; s < 8; ++s) {
            float dA = expf(dl * a[s]);
            h[s] = dA * h[s] + dx * bc[(j << 4) + s];
            y += h[s] * bc[(j << 4) + 8 + s];
        }
        float z = xz[(row << 9) + 256 + d];
        ybf[(row << 8) + d] = f2bf((y + xv * Dv) * siluf(z));
    }
}

// ---------------------------------------------------------------------------
// m2 xp partial reduction + split into dt(bf16)/B/C
__global__ void xp2_finish(const float* __restrict__ part, short* __restrict__ dtb,
                           float* __restrict__ Bs, float* __restrict__ Cs)
{
    int m = blockIdx.x, t = threadIdx.x;
    if (t >= 272) return;
    float s = 0.f;
    #pragma unroll
    for (int p = 0; p < 16; ++p) s += part[(size_t)p * 73728 + m * 288 + t];
    if (t < 256)       dtb[m * 256 + t] = f2bf(s);
    else if (t < 264)  Bs[m * 8 + t - 256] = s;
    else               Cs[m * 8 + t - 264] = s;
}

// m2 scan: 128 steps, thread per d (16384 chains)
__global__ __launch_bounds__(256) void scan2_kernel(const float* __restrict__ delta,
    const float* __restrict__ xc, const float* __restrict__ Bs,
    const float* __restrict__ Cs, const float* __restrict__ xz,
    const float* __restrict__ alog, const float* __restrict__ Dw,
    short* __restrict__ ybf)
{
    int b = blockIdx.x >> 5;
    int d = ((blockIdx.x & 31) << 8) + threadIdx.x;
    __shared__ float bc[2048];
    for (int i = threadIdx.x; i < 2048; i += 256) {
        int t = i >> 4, s = i & 15;
        bc[i] = (s < 8) ? Bs[((b << 7) + t) * 8 + s] : Cs[((b << 7) + t) * 8 + s - 8];
    }
    float a[8], h[8];
    #pragma unroll
    for (int s = 0; s < 8; ++s) { a[s] = -expf(alog[(size_t)d * 8 + s]); h[s] = 0.f; }
    float Dv = Dw[d];
    __syncthreads();
    for (int t = 0; t < 128; ++t) {
        size_t row = (b << 7) + t;
        float dl = delta[(row << 13) + d];
        float xv = xc[(row << 13) + d];
        float dx = dl * xv;
        float y = 0.f;
        #pragma unroll
        for (int s = 0; s < 8; ++s) {
            float dA = expf(dl * a[s]);
            h[s] = dA * h[s] + dx * bc[(t << 4) + s];
            y += h[s] * bc[(t << 4) + 8 + s];
        }
        float z = xz[(row << 14) + 8192 + d];
        ybf[(row << 13) + d] = f2bf((y + xv * Dv) * siluf(z));
    }
}

// ---------------------------------------------------------------------------
// out = x + transpose(y1out) + sum_p out2_part[p]
__global__ __launch_bounds__(256) void final_kernel(const float* __restrict__ x,
    const float* __restrict__ y1out, const float* __restrict__ part2,
    float* __restrict__ out)
{
    __shared__ float tl[64 * 65];
    int bz = blockIdx.x;
    int b = bz >> 7, rem = bz & 127;
    int c0 = (rem >> 6) << 6, l0 = (rem & 63) << 6;
    int t = threadIdx.x;
    int lrow = t >> 4, cq = (t & 15) << 2;
    #pragma unroll
    for (int jj = 0; jj < 4; ++jj) {
        int l = l0 + lrow + jj * 16;
        f32x4 v = *(const f32x4*)&y1out[((size_t)((b << 12) + l) << 7) + c0 + cq];
        #pragma unroll
        for (int i = 0; i < 4; ++i) tl[(cq + i) * 65 + lrow + jj * 16] = v[i];
    }
    __syncthreads();
    int lc = t & 63, cr = t >> 6;
    for (int j = 0; j < 16; ++j) {
        int cl = j * 4 + cr;
        size_t addr = ((size_t)((b << 7) + c0 + cl) << 12) + l0 + lc;
        float v = x[addr] + tl[cl * 65 + lc];
        v += part2[addr] + part2[1048576 + addr] + part2[2 * 1048576 + addr] + part2[3 * 1048576 + addr];
        out[addr] = v;
    }
}

// ---------------------------------------------------------------------------
extern "C" void kernel_launch(void* const* d_in, const int* in_sizes, int n_in,
                              void* d_out, int out_size, void* d_ws, size_t ws_size,
                              hipStream_t stream)
{
    (void)in_sizes; (void)n_in; (void)out_size; (void)ws_size;
    const float* x        = (const float*)d_in[0];
    const float* ln1_g    = (const float*)d_in[1];
    const float* ln1_b    = (const float*)d_in[2];
    const float* ln2_g    = (const float*)d_in[3];
    const float* ln2_b    = (const float*)d_in[4];
    const float* m1_in_w  = (const float*)d_in[5];
    const float* m1_cw    = (const float*)d_in[6];
    const float* m1_cb    = (const float*)d_in[7];
    const float* m1_xp_w  = (const float*)d_in[8];
    const float* m1_dt_w  = (const float*)d_in[9];
    const float* m1_dt_b  = (const float*)d_in[10];
    const float* m1_Alog  = (const float*)d_in[11];
    const float* m1_D     = (const float*)d_in[12];
    const float* m1_out_w = (const float*)d_in[13];
    const float* m2_in_w  = (const float*)d_in[14];
    const float* m2_cw    = (const float*)d_in[15];
    const float* m2_cb    = (const float*)d_in[16];
    const float* m2_xp_w  = (const float*)d_in[17];
    const float* m2_dt_w  = (const float*)d_in[18];
    const float* m2_dt_b  = (const float*)d_in[19];
    const float* m2_Alog  = (const float*)d_in[20];
    const float* m2_D     = (const float*)d_in[21];
    const float* m2_out_w = (const float*)d_in[22];
    float* out = (float*)d_out;

    char* wsp = (char*)d_ws;
    size_t off = 0;
    auto alloc = [&](size_t bytes) -> void* {
        void* p = wsp + off;
        off += (bytes + 255) & ~(size_t)255;
        return p;
    };

    // persistent across m1/m2 phases
    float* y1out = (float*)alloc((size_t)8192 * 128 * 4);
    size_t off0 = off;

    // ---- phase m1 buffers (aliased later by m2) ----
    short* xln1   = (short*)alloc((size_t)8192 * 128 * 2);
    float* xz1    = (float*)alloc((size_t)8192 * 512 * 4);
    float* xc1f   = (float*)alloc((size_t)8192 * 256 * 4);
    short* xc1b   = (short*)alloc((size_t)8192 * 256 * 2);
    float* dbl1   = (float*)alloc((size_t)8192 * 32 * 4);
    float* delta1 = (float*)alloc((size_t)8192 * 256 * 4);
    float* hch    = (float*)alloc((size_t)128 * 2048 * 4);
    float* pch    = (float*)alloc((size_t)128 * 2048 * 4);
    float* hin    = (float*)alloc((size_t)128 * 2048 * 4);
    short* y1b    = (short*)alloc((size_t)8192 * 256 * 2);

    ln1_kernel<<<128, 256, 0, stream>>>(x, ln1_g, ln1_b, xln1);
    gemm_bt<256, 64, 0><<<dim3(8, 32, 1), 256, 0, stream>>>(xln1, m1_in_w, xz1, nullptr, 8192, 512, 128, 128, 512);
    conv1_kernel<<<8192, 256, 0, stream>>>(xz1, m1_cw, m1_cb, xc1f, xc1b);
    gemm_bt<128, 32, 0><<<dim3(1, 64, 1), 256, 0, stream>>>(xc1b, m1_xp_w, dbl1, nullptr, 8192, 24, 256, 256, 32);
    dtproj1_kernel<<<8192, 256, 0, stream>>>(dbl1, m1_dt_w, m1_dt_b, delta1);
    scan1_p1<<<128, 256, 0, stream>>>(delta1, xc1f, dbl1, m1_Alog, hch, pch);
    scan1_p2<<<16, 256, 0, stream>>>(hch, pch, hin);
    scan1_p3<<<128, 256, 0, stream>>>(delta1, xc1f, dbl1, m1_Alog, hin, m1_D, xz1, y1b);
    gemm_bt<128, 64, 0><<<dim3(2, 64, 1), 256, 0, stream>>>(y1b, m1_out_w, y1out, nullptr, 8192, 128, 256, 256, 128);

    // ---- phase m2: reuse scratch region ----
    off = off0;
    short* xln2   = (short*)alloc((size_t)256 * 4096 * 2);
    float* xz2    = (float*)alloc((size_t)256 * 16384 * 4);
    float* xc2f   = (float*)alloc((size_t)256 * 8192 * 4);
    short* xc2b   = (short*)alloc((size_t)256 * 8192 * 2);
    float* xp2p   = (float*)alloc((size_t)16 * 256 * 288 * 4);
    short* dt2b   = (short*)alloc((size_t)256 * 256 * 2);
    float* Bs2    = (float*)alloc((size_t)256 * 8 * 4);
    float* Cs2    = (float*)alloc((size_t)256 * 8 * 4);
    float* delta2 = (float*)alloc((size_t)256 * 8192 * 4);
    short* y2b    = (short*)alloc((size_t)256 * 8192 * 2);
    float* out2p  = (float*)alloc((size_t)4 * 256 * 4096 * 4);

    ln2_kernel<<<256, 256, 0, stream>>>(x, ln2_g, ln2_b, xln2);
    gemm_bt<256, 32, 0><<<dim3(512, 1, 1), 256, 0, stream>>>(xln2, m2_in_w, xz2, nullptr, 256, 16384, 4096, 4096, 16384);
    conv2_kernel<<<8192, 256, 0, stream>>>(xz2, m2_cw, m2_cb, xc2f, xc2b);
    gemm_bt<256, 32, 0><<<dim3(9, 1, 16), 256, 0, stream>>>(xc2b, m2_xp_w, xp2p, nullptr, 256, 272, 8192, 512, 288);
    xp2_finish<<<256, 288, 0, stream>>>(xp2p, dt2b, Bs2, Cs2);
    gemm_bt<256, 32, 1><<<dim3(256, 1, 1), 256, 0, stream>>>(dt2b, m2_dt_w, delta2, m2_dt_b, 256, 8192, 256, 256, 8192);
    scan2_kernel<<<64, 256, 0, stream>>>(delta2, xc2f, Bs2, Cs2, xz2, m2_Alog, m2_D, y2b);
    gemm_bt<256, 32, 0><<<dim3(128, 1, 4), 256, 0, stream>>>(y2b, m2_out_w, out2p, nullptr, 256, 4096, 8192, 2048, 4096);
    final_kernel<<<256, 256, 0, stream>>>(x, y1out, out2p, out);
}

// Round 2
// 831.925 us; speedup vs baseline: 1.1051x; 1.1051x over previous
//
#include <hip/hip_runtime.h>
#include <math.h>

typedef __attribute__((ext_vector_type(8))) short s16x8;
typedef __attribute__((ext_vector_type(4))) short s16x4;
typedef __attribute__((ext_vector_type(4))) float f32x4;

#define DEVINL __device__ __forceinline__

DEVINL short f2bf(float f) {
    unsigned u = __float_as_uint(f);
    u += 0x7fffu + ((u >> 16) & 1u);   // RNE (finite values)
    return (short)(u >> 16);
}
DEVINL float softplusf(float x) { return (x > 20.f) ? x : log1pf(expf(x)); }
DEVINL float siluf(float z) { return z / (1.f + expf(-z)); }

typedef __attribute__((address_space(1))) const unsigned GblU32;
typedef __attribute__((address_space(3))) unsigned LdsU32;
DEVINL void gload_lds16(const void* g, void* l) {
    __builtin_amdgcn_global_load_lds((GblU32*)g, (LdsU32*)l, 16, 0, 0);
}

// ---------------------------------------------------------------------------
// LN over C=128 for each (b,l), reading x[b,c,l] (transposed) -> bf16 [8192,128]
__global__ __launch_bounds__(256) void ln1_kernel(const float* __restrict__ x,
    const float* __restrict__ g, const float* __restrict__ bb, short* __restrict__ out)
{
    __shared__ float tile[64 * 129];
    int b = blockIdx.x >> 6;
    int l0 = (blockIdx.x & 63) << 6;
    int t = threadIdx.x;
    int ll = t & 63, c0 = t >> 6;
    for (int c = c0; c < 128; c += 4)
        tile[ll * 129 + c] = x[((size_t)(b * 128 + c) << 12) + l0 + ll];
    __syncthreads();
    int r = t >> 2, q = t & 3;
    float s1 = 0.f, s2 = 0.f;
    #pragma unroll 8
    for (int j = 0; j < 32; ++j) {
        float v = tile[r * 129 + q * 32 + j];
        s1 += v; s2 += v * v;
    }
    s1 += __shfl_xor(s1, 1); s2 += __shfl_xor(s2, 1);
    s1 += __shfl_xor(s1, 2); s2 += __shfl_xor(s2, 2);
    float mean = s1 * (1.f / 128.f);
    float var  = s2 * (1.f / 128.f) - mean * mean;
    float rstd = rsqrtf(var + 1e-5f);
    short* orow = out + ((size_t)((b << 12) + l0 + r) << 7);
    for (int j = 0; j < 32; j += 4) {
        int c = q * 32 + j;
        s16x4 pk;
        #pragma unroll
        for (int i = 0; i < 4; ++i)
            pk[i] = f2bf((tile[r * 129 + c + i] - mean) * rstd * g[c + i] + bb[c + i]);
        *(s16x4*)&orow[c] = pk;
    }
}

// LN over L=4096 for each row m=(b,t) -> bf16 [256,4096]
__global__ __launch_bounds__(256) void ln2_kernel(const float* __restrict__ x,
    const float* __restrict__ g, const float* __restrict__ bb, short* __restrict__ out)
{
    int m = blockIdx.x, t = threadIdx.x;
    const float* row = x + (size_t)m * 4096;
    f32x4 vals[4];
    float s1 = 0.f, s2 = 0.f;
    #pragma unroll
    for (int j = 0; j < 4; ++j) {
        vals[j] = *(const f32x4*)(row + j * 1024 + t * 4);
        #pragma unroll
        for (int i = 0; i < 4; ++i) { s1 += vals[j][i]; s2 += vals[j][i] * vals[j][i]; }
    }
    #pragma unroll
    for (int off = 32; off; off >>= 1) { s1 += __shfl_xor(s1, off); s2 += __shfl_xor(s2, off); }
    __shared__ float red[8];
    int wv = t >> 6;
    if ((t & 63) == 0) { red[wv] = s1; red[4 + wv] = s2; }
    __syncthreads();
    s1 = red[0] + red[1] + red[2] + red[3];
    s2 = red[4] + red[5] + red[6] + red[7];
    float mean = s1 * (1.f / 4096.f);
    float var  = s2 * (1.f / 4096.f) - mean * mean;
    float rstd = rsqrtf(var + 1e-5f);
    short* orow = out + (size_t)m * 4096;
    #pragma unroll
    for (int j = 0; j < 4; ++j) {
        int idx = j * 1024 + t * 4;
        f32x4 gv = *(const f32x4*)(g + idx);
        f32x4 bv = *(const f32x4*)(bb + idx);
        s16x4 pk;
        #pragma unroll
        for (int i = 0; i < 4; ++i)
            pk[i] = f2bf((vals[j][i] - mean) * rstd * gv[i] + bv[i]);
        *(s16x4*)&orow[idx] = pk;
    }
}

// ---------------------------------------------------------------------------
// GEMM: C[m,n] = sum_k A[m,k]*W[n,k]. A bf16 [M,K] row-major (global_load_lds
// staged, XOR-swizzled), W fp32 [N,K] row-major (reg-staged -> cvt bf16 -> LDS).
// 256 threads = 4 waves arranged WM x WN; wave tile (BM/WM) x (BN/WN).
// 2-phase async prefetch: issue tile t+1 loads before computing tile t;
// one barrier per K-tile (BK=64).
template<int BM, int BN, int WM, int WN, int EPI>
__global__ __launch_bounds__(256) void gemm_bt(
    const short* __restrict__ A, const float* __restrict__ W,
    float* __restrict__ C, const float* __restrict__ bias,
    int M, int Nreal, int K, int kLen, int ldc)
{
    constexpr int FM = BM / (WM * 16);
    constexpr int FN = BN / (WN * 16);
    constexpr int NISSA = BM / 32;          // gload_lds16 issues per wave per tile
    constexpr int NW = (BN * 16) / 256;     // f32x4 W loads per thread per tile
    __shared__ short Al[2][BM * 64];
    __shared__ short Wl[2][BN * 64];
    const int tid = threadIdx.x;
    const int lane = tid & 63;
    const int wv = tid >> 6;
    const int lr = lane & 15, kh = lane >> 4;
    const int wm = wv % WM, wn = wv / WM;
    const int n0 = blockIdx.x * BN;
    const int m0 = blockIdx.y * BM;
    const int k0 = blockIdx.z * kLen;
    const int nt = kLen >> 6;
    const int srcSlot = (lane & 7) ^ (lane >> 3);   // inverse swizzle for gload_lds

    f32x4 acc[FM][FN];
    #pragma unroll
    for (int a = 0; a < FM; ++a)
        #pragma unroll
        for (int b = 0; b < FN; ++b) acc[a][b] = (f32x4){0.f, 0.f, 0.f, 0.f};
    f32x4 wreg[NW];

    auto stageA = [&](int buf, int kg) {
        #pragma unroll
        for (int i = 0; i < NISSA; ++i) {
            int c = wv * NISSA + i;
            int r = c * 8 + (lane >> 3);
            const short* src = A + (size_t)(m0 + r) * K + kg + srcSlot * 8;
            gload_lds16(src, &Al[buf][c * 512]);
        }
    };
    auto loadW = [&](int kg) {
        #pragma unroll
        for (int j = 0; j < NW; ++j) {
            int idx = j * 256 + tid;
            int row = idx >> 4, q = idx & 15;
            int gn = n0 + row;
            if (gn < Nreal) wreg[j] = *(const f32x4*)(W + (size_t)gn * K + kg + q * 4);
            else            wreg[j] = (f32x4){0.f, 0.f, 0.f, 0.f};
        }
    };
    auto writeW = [&](int buf) {
        #pragma unroll
        for (int j = 0; j < NW; ++j) {
            int idx = j * 256 + tid;
            int row = idx >> 4, q = idx & 15;
            s16x4 pk;
            #pragma unroll
            for (int i = 0; i < 4; ++i) pk[i] = f2bf(wreg[j][i]);
            int byte = row * 128 + (((q >> 1) ^ (row & 7)) << 4) + ((q & 1) << 3);
            *(s16x4*)((char*)&Wl[buf][0] + byte) = pk;
        }
    };
    auto compute = [&](int buf) {
        #pragma unroll
        for (int ks = 0; ks < 2; ++ks) {
            s16x8 af[FM], bfr[FN];
            #pragma unroll
            for (int mi = 0; mi < FM; ++mi) {
                int r = wm * (BM / WM) + mi * 16 + lr;
                int byte = r * 128 + (((ks * 4 + kh) ^ (r & 7)) << 4);
                af[mi] = *(const s16x8*)((const char*)&Al[buf][0] + byte);
            }
            #pragma unroll
            for (int ni = 0; ni < FN; ++ni) {
                int w = wn * (BN / WN) + ni * 16 + lr;
                int byte = w * 128 + (((ks * 4 + kh) ^ (w & 7)) << 4);
                bfr[ni] = *(const s16x8*)((const char*)&Wl[buf][0] + byte);
            }
            #pragma unroll
            for (int mi = 0; mi < FM; ++mi)
                #pragma unroll
                for (int ni = 0; ni < FN; ++ni)
                    acc[mi][ni] = __builtin_amdgcn_mfma_f32_16x16x32_bf16(
                        af[mi], bfr[ni], acc[mi][ni], 0, 0, 0);
        }
    };

    // prologue: stage tile 0 fully
    loadW(k0);
    stageA(0, k0);
    writeW(0);
    __syncthreads();

    int cur = 0;
    for (int t = 0; t < nt; ++t) {
        const int kn = k0 + (t + 1) * 64;
        if (t + 1 < nt) { loadW(kn); stageA(cur ^ 1, kn); }
        compute(cur);
        if (t + 1 < nt) writeW(cur ^ 1);
        __syncthreads();
        cur ^= 1;
    }

    float* Cz = C + (size_t)blockIdx.z * M * ldc;
    #pragma unroll
    for (int mi = 0; mi < FM; ++mi) {
        #pragma unroll
        for (int ni = 0; ni < FN; ++ni) {
            int gn = n0 + wn * (BN / WN) + ni * 16 + lr;
            if (gn < Nreal) {
                #pragma unroll
                for (int j = 0; j < 4; ++j) {
                    int gm = m0 + wm * (BM / WM) + mi * 16 + kh * 4 + j;
                    float v = acc[mi][ni][j];
                    if constexpr (EPI == 1) v = softplusf(v + bias[gn]);
                    Cz[(size_t)gm * ldc + gn] = v;
                }
            }
        }
    }
}

// ---------------------------------------------------------------------------
// depthwise causal conv (K=4) + silu; m1: seq=4096,d=256
__global__ __launch_bounds__(256) void conv1_kernel(const float* __restrict__ xz,
    const float* __restrict__ cw, const float* __restrict__ cb,
    float* __restrict__ xcf, short* __restrict__ xcb)
{
    int idx = blockIdx.x * 256 + threadIdx.x;      // 2*4096*256
    int d = idx & 255;
    int l = (idx >> 8) & 4095;
    int b = idx >> 20;
    f32x4 wv = *(const f32x4*)(cw + d * 4);
    float acc = cb[d];
    #pragma unroll
    for (int j = 0; j < 4; ++j) {
        int ll = l - 3 + j;
        if (ll >= 0) acc += xz[((size_t)((b << 12) + ll) << 9) + d] * wv[j];
    }
    acc = siluf(acc);
    size_t o = ((size_t)((b << 12) + l) << 8) + d;
    xcf[o] = acc;
    xcb[o] = f2bf(acc);
}

// m2: seq=128, d=8192
__global__ __launch_bounds__(256) void conv2_kernel(const float* __restrict__ xz,
    const float* __restrict__ cw, const float* __restrict__ cb,
    float* __restrict__ xcf, short* __restrict__ xcb)
{
    int idx = blockIdx.x * 256 + threadIdx.x;      // 2*128*8192
    int d = idx & 8191;
    int t = (idx >> 13) & 127;
    int b = idx >> 20;
    f32x4 wv = *(const f32x4*)(cw + d * 4);
    float acc = cb[d];
    #pragma unroll
    for (int j = 0; j < 4; ++j) {
        int tt = t - 3 + j;
        if (tt >= 0) acc += xz[((size_t)((b << 7) + tt) << 14) + d] * wv[j];
    }
    acc = siluf(acc);
    size_t o = ((size_t)((b << 7) + t) << 13) + d;
    xcf[o] = acc;
    xcb[o] = f2bf(acc);
}

// ---------------------------------------------------------------------------
// m1 delta: softplus(dt[m,0:8] @ dt_w[d,0:8]^T + dt_b[d]) -> [8192,256]
__global__ __launch_bounds__(256) void dtproj1_kernel(const float* __restrict__ dbl,
    const float* __restrict__ dtw, const float* __restrict__ dtb, float* __restrict__ delta)
{
    int m = blockIdx.x;
    int d = threadIdx.x;
    const float* dtv = dbl + (size_t)m * 32;
    f32x4 w0 = *(const f32x4*)(dtw + d * 8);
    f32x4 w1 = *(const f32x4*)(dtw + d * 8 + 4);
    float acc = dtb[d];
    #pragma unroll
    for (int j = 0; j < 4; ++j) acc += dtv[j] * w0[j];
    #pragma unroll
    for (int j = 0; j < 4; ++j) acc += dtv[4 + j] * w1[j];
    delta[(size_t)m * 256 + d] = softplusf(acc);
}

// ---------------------------------------------------------------------------
// m1 chunked scan: 128 chunks x 32 steps. dbl row stride 32: B at +8, C at +16.
__global__ __launch_bounds__(256) void scan1_p1(const float* __restrict__ delta,
    const float* __restrict__ xc, const float* __restrict__ dbl,
    const float* __restrict__ alog, float* __restrict__ hch, float* __restrict__ pch)
{
    int b = blockIdx.x >> 7, ch = blockIdx.x & 127;
    int d = threadIdx.x;
    __shared__ float bc[512];
    for (int i = threadIdx.x; i < 512; i += 256) {
        int j = i >> 4, s = i & 15;
        bc[i] = dbl[(size_t)((b << 12) + (ch << 5) + j) * 32 + 8 + s];
    }
    float a[8], h[8], P[8];
    #pragma unroll
    for (int s = 0; s < 8; ++s) { a[s] = -expf(alog[d * 8 + s]); h[s] = 0.f; P[s] = 1.f; }
    __syncthreads();
    for (int j = 0; j < 32; ++j) {
        size_t row = (b << 12) + (ch << 5) + j;
        float dl = delta[(row << 8) + d];
        float xv = xc[(row << 8) + d];
        float dx = dl * xv;
        #pragma unroll
        for (int s = 0; s < 8; ++s) {
            float dA = expf(dl * a[s]);
            h[s] = dA * h[s] + dx * bc[(j << 4) + s];
            P[s] *= dA;
        }
    }
    size_t base = (((size_t)((b << 7) + ch) << 8) + d) << 3;
    #pragma unroll
    for (int s = 0; s < 8; ++s) { hch[base + s] = h[s]; pch[base + s] = P[s]; }
}

__global__ __launch_bounds__(256) void scan1_p2(const float* __restrict__ hch,
    const float* __restrict__ pch, float* __restrict__ hin)
{
    int b = blockIdx.x >> 3;
    int idx = ((blockIdx.x & 7) << 8) + threadIdx.x;   // 0..2047 = d*8+s
    float h = 0.f;
    size_t o0 = (((size_t)(b << 7)) << 11) + idx;
    float pc = pch[o0], hc = hch[o0];
    for (int c = 0; c < 128; ++c) {
        size_t o = (((size_t)((b << 7) + c)) << 11) + idx;
        float pn = 0.f, hn = 0.f;
        if (c < 127) { pn = pch[o + 2048]; hn = hch[o + 2048]; }
        hin[o] = h;
        h = pc * h + hc;
        pc = pn; hc = hn;
    }
}

__global__ __launch_bounds__(256) void scan1_p3(const float* __restrict__ delta,
    const float* __restrict__ xc, const float* __restrict__ dbl,
    const float* __restrict__ alog, const float* __restrict__ hin,
    const float* __restrict__ Dw, const float* __restrict__ xz,
    short* __restrict__ ybf)
{
    int b = blockIdx.x >> 7, ch = blockIdx.x & 127;
    int d = threadIdx.x;
    __shared__ float bc[512];
    for (int i = threadIdx.x; i < 512; i += 256) {
        int j = i >> 4, s = i & 15;
        bc[i] = dbl[(size_t)((b << 12) + (ch << 5) + j) * 32 + 8 + s];
    }
    float a[8], h[8];
    size_t base = (((size_t)((b << 7) + ch) << 8) + d) << 3;
    #pragma unroll
    for (int s = 0; s < 8; ++s) { a[s] = -expf(alog[d * 8 + s]); h[s] = hin[base + s]; }
    float Dv = Dw[d];
    __syncthreads();
    for (int j = 0; j < 32; ++j) {
        size_t row = (b << 12) + (ch << 5) + j;
        float dl = delta[(row << 8) + d];
        float xv = xc[(row << 8) + d];
        float dx = dl * xv;
        float y = 0.f;
        #pragma unroll
        for (int s = 0; s < 8; ++s) {
            float dA = expf(dl * a[s]);
            h[s] = dA * h[s] + dx * bc[(j << 4) + s];
            y += h[s] * bc[(j << 4) + 8 + s];
        }
        float z = xz[(row << 9) + 256 + d];
        ybf[(row << 8) + d] = f2bf((y + xv * Dv) * siluf(z));
    }
}

// ---------------------------------------------------------------------------
// m2 xp partial reduction + split into dt(bf16)/B/C   (32 split-K parts)
__global__ void xp2_finish(const float* __restrict__ part, short* __restrict__ dtb,
                           float* __restrict__ Bs, float* __restrict__ Cs)
{
    int m = blockIdx.x, t = threadIdx.x;
    if (t >= 272) return;
    float s = 0.f;
    #pragma unroll
    for (int p = 0; p < 32; ++p) s += part[(size_t)p * 73728 + m * 288 + t];
    if (t < 256)       dtb[m * 256 + t] = f2bf(s);
    else if (t < 264)  Bs[m * 8 + t - 256] = s;
    else               Cs[m * 8 + t - 264] = s;
}

// m2 scan: 128 steps; 256 blocks x 64 threads (one chain per thread)
__global__ __launch_bounds__(64) void scan2_kernel(const float* __restrict__ delta,
    const float* __restrict__ xc, const float* __restrict__ Bs,
    const float* __restrict__ Cs, const float* __restrict__ xz,
    const float* __restrict__ alog, const float* __restrict__ Dw,
    short* __restrict__ ybf)
{
    int b = blockIdx.x >> 7;
    int d = ((blockIdx.x & 127) << 6) + threadIdx.x;
    __shared__ float bc[2048];
    for (int i = threadIdx.x; i < 2048; i += 64) {
        int t = i >> 4, s = i & 15;
        bc[i] = (s < 8) ? Bs[((b << 7) + t) * 8 + s] : Cs[((b << 7) + t) * 8 + s - 8];
    }
    float a[8], h[8];
    #pragma unroll
    for (int s = 0; s < 8; ++s) { a[s] = -expf(alog[(size_t)d * 8 + s]); h[s] = 0.f; }
    float Dv = Dw[d];
    __syncthreads();
    for (int t = 0; t < 128; ++t) {
        size_t row = (b << 7) + t;
        float dl = delta[(row << 13) + d];
        float xv = xc[(row << 13) + d];
        float dx = dl * xv;
        float y = 0.f;
        #pragma unroll
        for (int s = 0; s < 8; ++s) {
            float dA = expf(dl * a[s]);
            h[s] = dA * h[s] + dx * bc[(t << 4) + s];
            y += h[s] * bc[(t << 4) + 8 + s];
        }
        float z = xz[(row << 14) + 8192 + d];
        ybf[(row << 13) + d] = f2bf((y + xv * Dv) * siluf(z));
    }
}

// ---------------------------------------------------------------------------
// out = x + transpose(y1out) + sum_p out2_part[p]
__global__ __launch_bounds__(256) void final_kernel(const float* __restrict__ x,
    const float* __restrict__ y1out, const float* __restrict__ part2,
    float* __restrict__ out)
{
    __shared__ float tl[64 * 65];
    int bz = blockIdx.x;
    int b = bz >> 7, rem = bz & 127;
    int c0 = (rem >> 6) << 6, l0 = (rem & 63) << 6;
    int t = threadIdx.x;
    int lrow = t >> 4, cq = (t & 15) << 2;
    #pragma unroll
    for (int jj = 0; jj < 4; ++jj) {
        int l = l0 + lrow + jj * 16;
        f32x4 v = *(const f32x4*)&y1out[((size_t)((b << 12) + l) << 7) + c0 + cq];
        #pragma unroll
        for (int i = 0; i < 4; ++i) tl[(cq + i) * 65 + lrow + jj * 16] = v[i];
    }
    __syncthreads();
    int lc = t & 63, cr = t >> 6;
    for (int j = 0; j < 16; ++j) {
        int cl = j * 4 + cr;
        size_t addr = ((size_t)((b << 7) + c0 + cl) << 12) + l0 + lc;
        float v = x[addr] + tl[cl * 65 + lc];
        v += part2[addr] + part2[1048576 + addr] + part2[2 * 1048576 + addr] + part2[3 * 1048576 + addr];
        out[addr] = v;
    }
}

// ---------------------------------------------------------------------------
extern "C" void kernel_launch(void* const* d_in, const int* in_sizes, int n_in,
                              void* d_out, int out_size, void* d_ws, size_t ws_size,
                              hipStream_t stream)
{
    (void)in_sizes; (void)n_in; (void)out_size; (void)ws_size;
    const float* x        = (const float*)d_in[0];
    const float* ln1_g    = (const float*)d_in[1];
    const float* ln1_b    = (const float*)d_in[2];
    const float* ln2_g    = (const float*)d_in[3];
    const float* ln2_b    = (const float*)d_in[4];
    const float* m1_in_w  = (const float*)d_in[5];
    const float* m1_cw    = (const float*)d_in[6];
    const float* m1_cb    = (const float*)d_in[7];
    const float* m1_xp_w  = (const float*)d_in[8];
    const float* m1_dt_w  = (const float*)d_in[9];
    const float* m1_dt_b  = (const float*)d_in[10];
    const float* m1_Alog  = (const float*)d_in[11];
    const float* m1_D     = (const float*)d_in[12];
    const float* m1_out_w = (const float*)d_in[13];
    const float* m2_in_w  = (const float*)d_in[14];
    const float* m2_cw    = (const float*)d_in[15];
    const float* m2_cb    = (const float*)d_in[16];
    const float* m2_xp_w  = (const float*)d_in[17];
    const float* m2_dt_w  = (const float*)d_in[18];
    const float* m2_dt_b  = (const float*)d_in[19];
    const float* m2_Alog  = (const float*)d_in[20];
    const float* m2_D     = (const float*)d_in[21];
    const float* m2_out_w = (const float*)d_in[22];
    float* out = (float*)d_out;

    char* wsp = (char*)d_ws;
    size_t off = 0;
    auto alloc = [&](size_t bytes) -> void* {
        void* p = wsp + off;
        off += (bytes + 255) & ~(size_t)255;
        return p;
    };

    // persistent across m1/m2 phases
    float* y1out = (float*)alloc((size_t)8192 * 128 * 4);
    size_t off0 = off;

    // ---- phase m1 buffers (aliased later by m2) ----
    short* xln1   = (short*)alloc((size_t)8192 * 128 * 2);
    float* xz1    = (float*)alloc((size_t)8192 * 512 * 4);
    float* xc1f   = (float*)alloc((size_t)8192 * 256 * 4);
    short* xc1b   = (short*)alloc((size_t)8192 * 256 * 2);
    float* dbl1   = (float*)alloc((size_t)8192 * 32 * 4);
    float* delta1 = (float*)alloc((size_t)8192 * 256 * 4);
    float* hch    = (float*)alloc((size_t)256 * 2048 * 4);
    float* pch    = (float*)alloc((size_t)256 * 2048 * 4);
    float* hin    = (float*)alloc((size_t)256 * 2048 * 4);
    short* y1b    = (short*)alloc((size_t)8192 * 256 * 2);

    ln1_kernel<<<128, 256, 0, stream>>>(x, ln1_g, ln1_b, xln1);
    gemm_bt<128, 64, 2, 2, 0><<<dim3(8, 64, 1), 256, 0, stream>>>(xln1, m1_in_w, xz1, nullptr, 8192, 512, 128, 128, 512);
    conv1_kernel<<<8192, 256, 0, stream>>>(xz1, m1_cw, m1_cb, xc1f, xc1b);
    gemm_bt<128, 32, 2, 2, 0><<<dim3(1, 64, 1), 256, 0, stream>>>(xc1b, m1_xp_w, dbl1, nullptr, 8192, 24, 256, 256, 32);
    dtproj1_kernel<<<8192, 256, 0, stream>>>(dbl1, m1_dt_w, m1_dt_b, delta1);
    scan1_p1<<<256, 256, 0, stream>>>(delta1, xc1f, dbl1, m1_Alog, hch, pch);
    scan1_p2<<<16, 256, 0, stream>>>(hch, pch, hin);
    scan1_p3<<<256, 256, 0, stream>>>(delta1, xc1f, dbl1, m1_Alog, hin, m1_D, xz1, y1b);
    gemm_bt<128, 64, 2, 2, 0><<<dim3(2, 64, 1), 256, 0, stream>>>(y1b, m1_out_w, y1out, nullptr, 8192, 128, 256, 256, 128);

    // ---- phase m2: reuse scratch region ----
    off = off0;
    short* xln2   = (short*)alloc((size_t)256 * 4096 * 2);
    float* xz2    = (float*)alloc((size_t)256 * 16384 * 4);
    float* xc2f   = (float*)alloc((size_t)256 * 8192 * 4);
    short* xc2b   = (short*)alloc((size_t)256 * 8192 * 2);
    float* xp2p   = (float*)alloc((size_t)32 * 256 * 288 * 4);
    short* dt2b   = (short*)alloc((size_t)256 * 256 * 2);
    float* Bs2    = (float*)alloc((size_t)256 * 8 * 4);
    float* Cs2    = (float*)alloc((size_t)256 * 8 * 4);
    float* delta2 = (float*)alloc((size_t)256 * 8192 * 4);
    short* y2b    = (short*)alloc((size_t)256 * 8192 * 2);
    float* out2p  = (float*)alloc((size_t)4 * 256 * 4096 * 4);

    ln2_kernel<<<256, 256, 0, stream>>>(x, ln2_g, ln2_b, xln2);
    gemm_bt<256, 64, 4, 1, 0><<<dim3(256, 1, 1), 256, 0, stream>>>(xln2, m2_in_w, xz2, nullptr, 256, 16384, 4096, 4096, 16384);
    conv2_kernel<<<8192, 256, 0, stream>>>(xz2, m2_cw, m2_cb, xc2f, xc2b);
    gemm_bt<256, 64, 4, 1, 0><<<dim3(5, 1, 32), 256, 0, stream>>>(xc2b, m2_xp_w, xp2p, nullptr, 256, 272, 8192, 256, 288);
    xp2_finish<<<256, 288, 0, stream>>>(xp2p, dt2b, Bs2, Cs2);
    gemm_bt<256, 64, 4, 1, 1><<<dim3(128, 1, 1), 256, 0, stream>>>(dt2b, m2_dt_w, delta2, m2_dt_b, 256, 8192, 256, 256, 8192);
    scan2_kernel<<<256, 64, 0, stream>>>(delta2, xc2f, Bs2, Cs2, xz2, m2_Alog, m2_D, y2b);
    gemm_bt<256, 64, 4, 1, 0><<<dim3(64, 1, 4), 256, 0, stream>>>(y2b, m2_out_w, out2p, nullptr, 256, 4096, 8192, 2048, 4096);
    final_kernel<<<256, 256, 0, stream>>>(x, y1out, out2p, out);
}